// Round 18
// baseline (74.801 us; speedup 1.0000x reference)
//
#include <hip/hip_runtime.h>
#include <math.h>

#define DIM 1024
#define NH 16
#define HD 64
#define SEQ 2048
#define CHUNK 128
#define NCHUNK (SEQ / CHUNK)   // 16
#define QKV_COLS (3 * DIM)     // 3072

typedef __attribute__((ext_vector_type(8))) short bf16x8;
typedef __attribute__((ext_vector_type(4))) float f32x4;

__device__ __forceinline__ unsigned short f2bf(float f) {
  unsigned int u = __float_as_uint(f);
  u += 0x7FFF + ((u >> 16) & 1);        // RNE
  return (unsigned short)(u >> 16);
}
__device__ __forceinline__ float bf2f(unsigned short s) {
  return __uint_as_float(((unsigned int)s) << 16);
}
// XOR swizzle: spreads row-major tiles (row stride >=128B) across banks
__device__ __forceinline__ int swzb(int byte, int row) {
  return byte ^ ((row & 7) << 4);
}

// ------------- fused f32 -> bf16 conversion, 4 float4 per thread -----------
// block ranges: x: [0,512), qkv_w: [512,1280), proj_w: [1280,1536)
__global__ __launch_bounds__(256) void convert_all(const float* __restrict__ x,
                                                   const float* __restrict__ qw,
                                                   const float* __restrict__ pw,
                                                   unsigned short* __restrict__ xb,
                                                   unsigned short* __restrict__ qwb,
                                                   unsigned short* __restrict__ pwb) {
  const int b = blockIdx.x;
  const float* in; unsigned short* out; int base;
  if (b < 512)       { in = x;  out = xb;  base = b * 1024; }
  else if (b < 1280) { in = qw; out = qwb; base = (b - 512) * 1024; }
  else               { in = pw; out = pwb; base = (b - 1280) * 1024; }
#pragma unroll
  for (int s = 0; s < 4; ++s) {
    const int i = base + s * 256 + threadIdx.x;
    float4 v = reinterpret_cast<const float4*>(in)[i];
    ushort4 o;
    o.x = f2bf(v.x); o.y = f2bf(v.y); o.z = f2bf(v.z); o.w = f2bf(v.w);
    reinterpret_cast<ushort4*>(out)[i] = o;
  }
}

// ------- paired-K NBUF=6 counted-vmcnt bf16 MFMA GEMM: C = A @ W^T ---------
// TWO K-tiles per barrier (R13/R17 density knee: >=8 MFMAs/barrier needed;
// pairing doubles density and halves barrier count at zero traffic change).
// Ledger (per wave, L=ACH+BCH loads/stage, 2 stages/pair): prologue stages
// tiles 0..3 (pairs 0,1). Iter p: vmcnt(2L) => pair p landed (pair p+1's
// loads stay in flight); barrier; stage pair p+2 into buffers (2p+4)%6,
// (2p+5)%6 (last read at iter p-1, behind the barrier); compute tiles
// 2p, 2p+1. Tail pair drains vmcnt(0).
// PHI: apply relu+1e-6 to output columns < 2*DIM (fused phi_q/phi_k).
// XCD-aware bijective chunked swizzle (T1): requires nwg % 8 == 0.
template <int BM, int BN, bool PHI, typename OutT>
__global__ __launch_bounds__(256) void gemm_paired(const unsigned short* __restrict__ A,
                                                   const unsigned short* __restrict__ W,
                                                   OutT* __restrict__ C,
                                                   int M, int Nn, int K) {
  constexpr int BK = 32;
  constexpr int NBUF = 6;
  constexpr int MFR = BM / 32;
  constexpr int NFR = BN / 32;
  constexpr int ACH = BM / 64;
  constexpr int BCH = BN / 64;
  constexpr int L = ACH + BCH;
  static_assert(L == 2 || L == 3, "vmcnt assumes L in {2,3}");
  __shared__ unsigned short As[NBUF][BM * BK];
  __shared__ unsigned short Bs[NBUF][BN * BK];
  const int tid  = threadIdx.x;
  const int lane = tid & 63;
  const int wv   = tid >> 6;
  const int nwg  = gridDim.x * gridDim.y;
  int wgid = blockIdx.y * gridDim.x + blockIdx.x;
  wgid = (wgid & 7) * (nwg >> 3) + (wgid >> 3);
  const int row0 = (wgid / gridDim.x) * BM;
  const int col0 = (wgid % gridDim.x) * BN;
  const int ln15 = lane & 15;
  const int lhi  = lane >> 4;
  const int wr = (wv >> 1) * (BM / 2);
  const int wc = (wv & 1) * (BN / 2);

  f32x4 acc[MFR][NFR] = {};

  auto stage = [&](int buf, int t) {
    const int k0 = t * BK;
#pragma unroll
    for (int tt = 0; tt < ACH; ++tt) {
      const int chunk = wv * ACH + tt;
      const int lid = chunk * 64 + lane;
      const int r  = lid >> 2;
      const int ke = (lid & 3) << 3;
      __builtin_amdgcn_global_load_lds(
          (const __attribute__((address_space(1))) void*)&A[(size_t)(row0 + r) * K + k0 + ke],
          (__attribute__((address_space(3))) void*)&As[buf][chunk * 512], 16, 0, 0);
    }
#pragma unroll
    for (int tt = 0; tt < BCH; ++tt) {
      const int chunk = wv * BCH + tt;
      const int lid = chunk * 64 + lane;
      const int r  = lid >> 2;
      const int ke = (lid & 3) << 3;
      __builtin_amdgcn_global_load_lds(
          (const __attribute__((address_space(1))) void*)&W[(size_t)(col0 + r) * K + k0 + ke],
          (__attribute__((address_space(3))) void*)&Bs[buf][chunk * 512], 16, 0, 0);
    }
  };

  const int nt = K / BK;                    // 32
  stage(0, 0); stage(1, 1); stage(2, 2); stage(3, 3);
  for (int p = 0; p < nt / 2; ++p) {        // 16 pairs
    if (p < nt / 2 - 1) {
      if constexpr (L == 3) asm volatile("s_waitcnt vmcnt(6)" ::: "memory");
      else                  asm volatile("s_waitcnt vmcnt(4)" ::: "memory");
    } else {
      asm volatile("s_waitcnt vmcnt(0)" ::: "memory");
    }
    __builtin_amdgcn_s_barrier();
    if (2 * p + 4 < nt) stage((2 * p + 4) % NBUF, 2 * p + 4);
    if (2 * p + 5 < nt) stage((2 * p + 5) % NBUF, 2 * p + 5);
#pragma unroll
    for (int half = 0; half < 2; ++half) {
      const int cur = (2 * p + half) % NBUF;
      bf16x8 a[MFR], b[NFR];
#pragma unroll
      for (int m = 0; m < MFR; ++m)
        a[m] = *reinterpret_cast<const bf16x8*>(&As[cur][(wr + m * 16 + ln15) * BK + lhi * 8]);
#pragma unroll
      for (int n = 0; n < NFR; ++n)
        b[n] = *reinterpret_cast<const bf16x8*>(&Bs[cur][(wc + n * 16 + ln15) * BK + lhi * 8]);
#pragma unroll
      for (int m = 0; m < MFR; ++m)
#pragma unroll
        for (int n = 0; n < NFR; ++n)
          acc[m][n] = __builtin_amdgcn_mfma_f32_16x16x32_bf16(a[m], b[n], acc[m][n], 0, 0, 0);
    }
  }

  const int crow = lhi * 4;           // m89-verified C/D layout
  const int ccol = ln15;
#pragma unroll
  for (int m = 0; m < MFR; ++m)
#pragma unroll
    for (int n = 0; n < NFR; ++n)
#pragma unroll
      for (int r = 0; r < 4; ++r) {
        const int gc = col0 + wc + n * 16 + ccol;
        float v = acc[m][n][r];
        if constexpr (PHI) {
          if (gc < 2 * DIM) v = fmaxf(v, 0.f) + 1e-6f;   // phi for Q,K columns
        }
        const size_t idx = (size_t)(row0 + wr + m * 16 + crow + r) * Nn + gc;
        if constexpr (sizeof(OutT) == 2) C[idx] = (OutT)f2bf(v);
        else                             C[idx] = v;
      }
}

// -------- MFMA per-(head,chunk) KV sums: ckv[h][c][d][e] = sum_r phik[r][d] v[r][e]
// (qkv K-columns already hold phi_k from GEMM1's fused epilogue)
__global__ __launch_bounds__(256) void ckv_mfma_kernel(const unsigned short* __restrict__ qkv,
                                                       float* __restrict__ ckv) {
  const int h = blockIdx.x / NCHUNK;
  const int c = blockIdx.x % NCHUNK;
  const int tid  = threadIdx.x;
  const int lane = tid & 63;
  const int w    = tid >> 6;        // wave = d-tile
  const int ln15 = lane & 15;
  const int lhi  = lane >> 4;

  __shared__ unsigned short kst[HD * CHUNK];   // phi_k^T [d][r] swizzled, 16 KB
  __shared__ unsigned short vt[HD * CHUNK];    // v^T     [e][r] swizzled, 16 KB

  for (int i = tid; i < CHUNK * HD / 4; i += 256) {   // 8 iters
    const int r = i >> 4;
    const int d4 = (i & 15) << 2;
    const size_t base = (size_t)(c * CHUNK + r) * QKV_COLS + h * HD + d4;
    ushort4 k4 = *reinterpret_cast<const ushort4*>(&qkv[base + DIM]);
    ushort4 v4 = *reinterpret_cast<const ushort4*>(&qkv[base + 2 * DIM]);
#pragma unroll
    for (int j = 0; j < 4; ++j) {
      const int d = d4 + j;
      *reinterpret_cast<unsigned short*>((char*)kst + swzb(d * 256 + r * 2, d)) = (&k4.x)[j];
      *reinterpret_cast<unsigned short*>((char*)vt + swzb(d * 256 + r * 2, d)) = (&v4.x)[j];
    }
  }
  __syncthreads();

  f32x4 acc[4] = {};
#pragma unroll
  for (int ks = 0; ks < 4; ++ks) {
    const int dr = w * 16 + ln15;
    bf16x8 a = *reinterpret_cast<const bf16x8*>((char*)kst + swzb(dr * 256 + (ks * 32 + lhi * 8) * 2, dr));
#pragma unroll
    for (int et = 0; et < 4; ++et) {
      const int er = et * 16 + ln15;
      bf16x8 b = *reinterpret_cast<const bf16x8*>((char*)vt + swzb(er * 256 + (ks * 32 + lhi * 8) * 2, er));
      acc[et] = __builtin_amdgcn_mfma_f32_16x16x32_bf16(a, b, acc[et], 0, 0, 0);
    }
  }
  const size_t base = (size_t)(h * NCHUNK + c) * (HD * HD);
#pragma unroll
  for (int et = 0; et < 4; ++et)
#pragma unroll
    for (int r = 0; r < 4; ++r)
      ckv[base + (size_t)(w * 16 + lhi * 4 + r) * HD + et * 16 + ln15] = acc[et][r];
}

// -------- MFMA attention (with inline exclusive prefix over ckv chunks) ----
// (qkv Q/K-columns already hold phi from GEMM1's fused epilogue)
__global__ __launch_bounds__(256) void attn_mfma_kernel(const unsigned short* __restrict__ qkv,
                                                        const float* __restrict__ ckv,
                                                        const float* __restrict__ alpha_log,
                                                        const float* __restrict__ beta_log,
                                                        unsigned short* __restrict__ attn_out) {
  const int h = blockIdx.x / NCHUNK;
  const int c = blockIdx.x % NCHUNK;
  const int tid  = threadIdx.x;
  const int lane = tid & 63;
  const int w    = tid >> 6;        // wave 0..3, owns rows w*32 .. w*32+31
  const int ln15 = lane & 15;
  const int lhi  = lane >> 4;       // 0..3

  __shared__ unsigned short ks[CHUNK * HD];      // phi_k [128][64] swizzled, 16 KB
  __shared__ unsigned short vst[HD * 256];       // [e][k]: 0..63 Sp_hi, 64..127 Sp_lo, 128..255 v^T; 32 KB
  __shared__ unsigned short ps[CHUNK * CHUNK];   // P [128][128] swizzled, 32 KB

  // ---- stage 1a: K/V into LDS + phi_q registers (issued FIRST so the
  //      global loads' latency hides under the prefix chain below) ----
  for (int i = tid; i < CHUNK * HD / 4; i += 256) {   // 8 iters
    const int r = i >> 4;
    const int d4 = (i & 15) << 2;
    const size_t base = (size_t)(c * CHUNK + r) * QKV_COLS + h * HD + d4;
    ushort4 k4 = *reinterpret_cast<const ushort4*>(&qkv[base + DIM]);
    ushort4 v4 = *reinterpret_cast<const ushort4*>(&qkv[base + 2 * DIM]);
    *reinterpret_cast<ushort4*>((char*)ks + swzb(r * 128 + d4 * 2, r)) = k4;
#pragma unroll
    for (int j = 0; j < 4; ++j) {
      const int e = d4 + j;
      *reinterpret_cast<unsigned short*>((char*)vst + swzb(e * 512 + (128 + r) * 2, e)) = (&v4.x)[j];
    }
  }
  bf16x8 qf[2][2];
#pragma unroll
  for (int m = 0; m < 2; ++m)
#pragma unroll
    for (int kk = 0; kk < 2; ++kk) {
      const size_t gq = (size_t)(c * CHUNK + w * 32 + m * 16 + ln15) * QKV_COLS
                        + h * HD + kk * 32 + lhi * 8;
      qf[m][kk] = *reinterpret_cast<const bf16x8*>(&qkv[gq]);
    }

  // ---- stage 1b: inline exclusive prefix: Sp = sum_{cc<c} ckv[h][cc] ----
  // 2-way unrolled: two independent chunk loads per iteration double the
  // ILP on the L2 load-latency chain (worst block c=15 halves its chain).
  {
    float sp[16];
#pragma unroll
    for (int p = 0; p < 16; ++p) sp[p] = 0.f;
    const float* cb = ckv + (size_t)h * NCHUNK * (HD * HD) + tid * 16;
    int cc = 0;
    for (; cc + 2 <= c; cc += 2) {
      const float4* pa = reinterpret_cast<const float4*>(cb + (size_t)cc * (HD * HD));
      const float4* pb = reinterpret_cast<const float4*>(cb + (size_t)(cc + 1) * (HD * HD));
#pragma unroll
      for (int q = 0; q < 4; ++q) {
        float4 t = pa[q];
        float4 u = pb[q];
        sp[q * 4 + 0] += t.x + u.x; sp[q * 4 + 1] += t.y + u.y;
        sp[q * 4 + 2] += t.z + u.z; sp[q * 4 + 3] += t.w + u.w;
      }
    }
    if (cc < c) {
      const float4* pa = reinterpret_cast<const float4*>(cb + (size_t)cc * (HD * HD));
#pragma unroll
      for (int q = 0; q < 4; ++q) {
        float4 t = pa[q];
        sp[q * 4 + 0] += t.x; sp[q * 4 + 1] += t.y;
        sp[q * 4 + 2] += t.z; sp[q * 4 + 3] += t.w;
      }
    }
    const int d = tid >> 2;
#pragma unroll
    for (int j = 0; j < 16; ++j) {
      const int e = (tid & 3) * 16 + j;
      const float sv = sp[j];
      const unsigned short hi = f2bf(sv);
      const unsigned short lo = f2bf(sv - bf2f(hi));
      *reinterpret_cast<unsigned short*>((char*)vst + swzb(e * 512 + d * 2, e)) = hi;
      *reinterpret_cast<unsigned short*>((char*)vst + swzb(e * 512 + (64 + d) * 2, e)) = lo;
    }
  }
  __syncthreads();

  // ---- stage 2: S = phi_q @ phi_k^T ----
  f32x4 accs[2][8] = {};
#pragma unroll
  for (int j = 0; j < 8; ++j) {
    const int col = j * 16 + ln15;
    bf16x8 b0 = *reinterpret_cast<const bf16x8*>((char*)ks + swzb(col * 128 + lhi * 16, col));
    bf16x8 b1 = *reinterpret_cast<const bf16x8*>((char*)ks + swzb(col * 128 + 64 + lhi * 16, col));
#pragma unroll
    for (int m = 0; m < 2; ++m) {
      accs[m][j] = __builtin_amdgcn_mfma_f32_16x16x32_bf16(qf[m][0], b0, accs[m][j], 0, 0, 0);
      accs[m][j] = __builtin_amdgcn_mfma_f32_16x16x32_bf16(qf[m][1], b1, accs[m][j], 0, 0, 0);
    }
  }
#pragma unroll
  for (int m = 0; m < 2; ++m)
#pragma unroll
    for (int j = 0; j < 8; ++j)
#pragma unroll
      for (int r = 0; r < 4; ++r) {
        const int qrow = w * 32 + m * 16 + lhi * 4 + r;
        const int kcol = j * 16 + ln15;
        const float val = (qrow >= kcol) ? accs[m][j][r] : 0.f;
        *reinterpret_cast<unsigned short*>((char*)ps + swzb(qrow * 256 + kcol * 2, qrow)) = f2bf(val);
      }
  __syncthreads();

  // ---- stage 3: out = [phi_q, phi_q, P] @ [Sp_hi; Sp_lo; v]  (K = 256) ----
  f32x4 acco[2][4] = {};
#pragma unroll
  for (int kk = 0; kk < 8; ++kk) {
    bf16x8 a[2];
    if (kk < 4) {
#pragma unroll
      for (int m = 0; m < 2; ++m) a[m] = qf[m][kk & 1];
    } else {
#pragma unroll
      for (int m = 0; m < 2; ++m) {
        const int row = w * 32 + m * 16 + ln15;
        a[m] = *reinterpret_cast<const bf16x8*>((char*)ps + swzb(row * 256 + (kk - 4) * 64 + lhi * 16, row));
      }
    }
#pragma unroll
    for (int ct = 0; ct < 4; ++ct) {
      const int e = ct * 16 + ln15;
      bf16x8 b = *reinterpret_cast<const bf16x8*>((char*)vst + swzb(e * 512 + kk * 64 + lhi * 16, e));
#pragma unroll
      for (int m = 0; m < 2; ++m)
        acco[m][ct] = __builtin_amdgcn_mfma_f32_16x16x32_bf16(a[m], b, acco[m][ct], 0, 0, 0);
    }
  }

  // ---- normalize + store ----
  const float ap = log1pf(expf(alpha_log[h])) + 1e-6f;
  const float bp = log1pf(expf(beta_log[h])) + 1e-6f;
  const float scale = ap * bp * 8.0f;     // sqrt(64)=8
#pragma unroll
  for (int m = 0; m < 2; ++m)
#pragma unroll
    for (int ct = 0; ct < 4; ++ct)
#pragma unroll
      for (int r = 0; r < 4; ++r) {
        const int n = c * CHUNK + w * 32 + m * 16 + lhi * 4 + r;
        const float inv = 1.0f / fmaxf(scale * (float)(n + 1), 1e-6f);
        attn_out[(size_t)n * DIM + h * HD + ct * 16 + ln15] = f2bf(acco[m][ct][r] * inv);
      }
}

extern "C" void kernel_launch(void* const* d_in, const int* in_sizes, int n_in,
                              void* d_out, int out_size, void* d_ws, size_t ws_size,
                              hipStream_t stream) {
  const float* x        = (const float*)d_in[0];
  const float* qkv_w    = (const float*)d_in[1];
  const float* proj_w   = (const float*)d_in[2];
  const float* alpha_lg = (const float*)d_in[3];
  const float* beta_lg  = (const float*)d_in[4];
  float* out = (float*)d_out;

  char* ws = (char*)d_ws;
  size_t off = 0;
  unsigned short* qkvb = (unsigned short*)(ws + off); off += (size_t)SEQ * QKV_COLS * 2;
  float*          ckv  = (float*)         (ws + off); off += (size_t)NH * NCHUNK * HD * HD * 4;
  unsigned short* attn = (unsigned short*)(ws + off); off += (size_t)SEQ * DIM * 2;
  unsigned short* xb   = (unsigned short*)(ws + off); off += (size_t)SEQ * DIM * 2;
  unsigned short* qwb  = (unsigned short*)(ws + off); off += (size_t)QKV_COLS * DIM * 2;
  unsigned short* pwb  = (unsigned short*)(ws + off); off += (size_t)DIM * DIM * 2;

  // 0) fused bf16 conversion (4 float4/thread)
  convert_all<<<1536, 256, 0, stream>>>(x, qkv_w, proj_w, xb, qwb, pwb);
  // 1) qkv = x @ qkv_w^T, phi fused (64x128 paired-K: 16 MFMAs/barrier,
  //    16 barriers, NBUF=6 -> 72 KB LDS, 2 blocks/CU, 768 blocks)
  gemm_paired<64, 128, true, unsigned short><<<dim3(QKV_COLS / 128, SEQ / 64), 256, 0, stream>>>(
      xb, qwb, qkvb, SEQ, QKV_COLS, DIM);
  // 2) per-chunk KV sums via MFMA
  ckv_mfma_kernel<<<NH * NCHUNK, 256, 0, stream>>>(qkvb, ckv);
  // 3) attention (inline prefix, loads-first + 2-way unrolled prefix)
  attn_mfma_kernel<<<NH * NCHUNK, 256, 0, stream>>>(qkvb, ckv, alpha_lg, beta_lg, attn);
  // 4) out = attn @ proj_w^T (64x64 paired-K, R17 proven config)
  gemm_paired<64, 64, false, float><<<dim3(DIM / 64, SEQ / 64), 256, 0, stream>>>(
      attn, pwb, out, SEQ, DIM, DIM);
}

// Round 19
// 66.642 us; speedup vs baseline: 1.1224x; 1.1224x over previous
//
#include <hip/hip_runtime.h>
#include <math.h>

#define DIM 1024
#define NH 16
#define HD 64
#define SEQ 2048
#define CHUNK 128
#define NCHUNK (SEQ / CHUNK)   // 16
#define QKV_COLS (3 * DIM)     // 3072

typedef __attribute__((ext_vector_type(8))) short bf16x8;
typedef __attribute__((ext_vector_type(4))) float f32x4;

__device__ __forceinline__ unsigned short f2bf(float f) {
  unsigned int u = __float_as_uint(f);
  u += 0x7FFF + ((u >> 16) & 1);        // RNE
  return (unsigned short)(u >> 16);
}
__device__ __forceinline__ float bf2f(unsigned short s) {
  return __uint_as_float(((unsigned int)s) << 16);
}
// XOR swizzle: spreads row-major tiles (row stride >=128B) across banks
__device__ __forceinline__ int swzb(int byte, int row) {
  return byte ^ ((row & 7) << 4);
}

// ------------- fused f32 -> bf16 conversion, 4 float4 per thread -----------
// block ranges: x: [0,512), qkv_w: [512,1280), proj_w: [1280,1536)
__global__ __launch_bounds__(256) void convert_all(const float* __restrict__ x,
                                                   const float* __restrict__ qw,
                                                   const float* __restrict__ pw,
                                                   unsigned short* __restrict__ xb,
                                                   unsigned short* __restrict__ qwb,
                                                   unsigned short* __restrict__ pwb) {
  const int b = blockIdx.x;
  const float* in; unsigned short* out; int base;
  if (b < 512)       { in = x;  out = xb;  base = b * 1024; }
  else if (b < 1280) { in = qw; out = qwb; base = (b - 512) * 1024; }
  else               { in = pw; out = pwb; base = (b - 1280) * 1024; }
#pragma unroll
  for (int s = 0; s < 4; ++s) {
    const int i = base + s * 256 + threadIdx.x;
    float4 v = reinterpret_cast<const float4*>(in)[i];
    ushort4 o;
    o.x = f2bf(v.x); o.y = f2bf(v.y); o.z = f2bf(v.z); o.w = f2bf(v.w);
    reinterpret_cast<ushort4*>(out)[i] = o;
  }
}

// ------- NBUF-deep counted-vmcnt bf16 MFMA GEMM: C = A @ W^T ---------------
// PHI: apply relu+1e-6 to output columns < 2*DIM (fused phi_q/phi_k).
// XCD-aware bijective chunked swizzle (T1): requires nwg % 8 == 0.
// GEMM1 config (above the 8-MFMAs/barrier density knee): unpaired, NBUF=4,
// 48 KB LDS -> 3 blocks/CU. R18 showed pairing here costs TLP and regresses.
template <int BM, int BN, int NBUF, bool PHI, typename OutT>
__global__ __launch_bounds__(256) void gemmN_bt(const unsigned short* __restrict__ A,
                                                const unsigned short* __restrict__ W,
                                                OutT* __restrict__ C,
                                                int M, int Nn, int K) {
  constexpr int BK = 32;
  constexpr int MFR = BM / 32;
  constexpr int NFR = BN / 32;
  constexpr int ACH = BM / 64;
  constexpr int BCH = BN / 64;
  constexpr int L = ACH + BCH;
  static_assert(L == 2 || L == 3, "vmcnt ladder assumes L in {2,3}");
  __shared__ unsigned short As[NBUF][BM * BK];
  __shared__ unsigned short Bs[NBUF][BN * BK];
  const int tid  = threadIdx.x;
  const int lane = tid & 63;
  const int wv   = tid >> 6;
  const int nwg  = gridDim.x * gridDim.y;
  int wgid = blockIdx.y * gridDim.x + blockIdx.x;
  wgid = (wgid & 7) * (nwg >> 3) + (wgid >> 3);
  const int row0 = (wgid / gridDim.x) * BM;
  const int col0 = (wgid % gridDim.x) * BN;
  const int ln15 = lane & 15;
  const int lhi  = lane >> 4;
  const int wr = (wv >> 1) * (BM / 2);
  const int wc = (wv & 1) * (BN / 2);

  f32x4 acc[MFR][NFR] = {};

  auto stage = [&](int buf, int t) {
    const int k0 = t * BK;
#pragma unroll
    for (int tt = 0; tt < ACH; ++tt) {
      const int chunk = wv * ACH + tt;
      const int lid = chunk * 64 + lane;
      const int r  = lid >> 2;
      const int ke = (lid & 3) << 3;
      __builtin_amdgcn_global_load_lds(
          (const __attribute__((address_space(1))) void*)&A[(size_t)(row0 + r) * K + k0 + ke],
          (__attribute__((address_space(3))) void*)&As[buf][chunk * 512], 16, 0, 0);
    }
#pragma unroll
    for (int tt = 0; tt < BCH; ++tt) {
      const int chunk = wv * BCH + tt;
      const int lid = chunk * 64 + lane;
      const int r  = lid >> 2;
      const int ke = (lid & 3) << 3;
      __builtin_amdgcn_global_load_lds(
          (const __attribute__((address_space(1))) void*)&W[(size_t)(col0 + r) * K + k0 + ke],
          (__attribute__((address_space(3))) void*)&Bs[buf][chunk * 512], 16, 0, 0);
    }
  };

  const int nt = K / BK;
#pragma unroll
  for (int i = 0; i < NBUF - 1; ++i) stage(i, i);
  // Ledger (per wave, L loads/stage): entering iter t, stages for tiles
  // t..t+NBUF-2 in flight. vmcnt(k*L), k = min(NBUF-2, nt-1-t) => tile t
  // landed; barrier; stage(t+NBUF-1) into freed buffer; compute tile t.
  for (int t = 0; t < nt; ++t) {
    const int k = (nt - 1 - t) < (NBUF - 2) ? (nt - 1 - t) : (NBUF - 2);
    if constexpr (L == 3) {
      switch (k) {
        case 4:  asm volatile("s_waitcnt vmcnt(12)" ::: "memory"); break;
        case 3:  asm volatile("s_waitcnt vmcnt(9)"  ::: "memory"); break;
        case 2:  asm volatile("s_waitcnt vmcnt(6)"  ::: "memory"); break;
        case 1:  asm volatile("s_waitcnt vmcnt(3)"  ::: "memory"); break;
        default: asm volatile("s_waitcnt vmcnt(0)"  ::: "memory"); break;
      }
    } else {
      switch (k) {
        case 4:  asm volatile("s_waitcnt vmcnt(8)"  ::: "memory"); break;
        case 3:  asm volatile("s_waitcnt vmcnt(6)"  ::: "memory"); break;
        case 2:  asm volatile("s_waitcnt vmcnt(4)"  ::: "memory"); break;
        case 1:  asm volatile("s_waitcnt vmcnt(2)"  ::: "memory"); break;
        default: asm volatile("s_waitcnt vmcnt(0)"  ::: "memory"); break;
      }
    }
    __builtin_amdgcn_s_barrier();
    if (t + NBUF - 1 < nt) stage((t + NBUF - 1) % NBUF, t + NBUF - 1);
    const int cur = t % NBUF;
    bf16x8 a[MFR], b[NFR];
#pragma unroll
    for (int m = 0; m < MFR; ++m)
      a[m] = *reinterpret_cast<const bf16x8*>(&As[cur][(wr + m * 16 + ln15) * BK + lhi * 8]);
#pragma unroll
    for (int n = 0; n < NFR; ++n)
      b[n] = *reinterpret_cast<const bf16x8*>(&Bs[cur][(wc + n * 16 + ln15) * BK + lhi * 8]);
#pragma unroll
    for (int m = 0; m < MFR; ++m)
#pragma unroll
      for (int n = 0; n < NFR; ++n)
        acc[m][n] = __builtin_amdgcn_mfma_f32_16x16x32_bf16(a[m], b[n], acc[m][n], 0, 0, 0);
  }

  const int crow = lhi * 4;           // m89-verified C/D layout
  const int ccol = ln15;
#pragma unroll
  for (int m = 0; m < MFR; ++m)
#pragma unroll
    for (int n = 0; n < NFR; ++n)
#pragma unroll
      for (int r = 0; r < 4; ++r) {
        const int gc = col0 + wc + n * 16 + ccol;
        float v = acc[m][n][r];
        if constexpr (PHI) {
          if (gc < 2 * DIM) v = fmaxf(v, 0.f) + 1e-6f;   // phi for Q,K columns
        }
        const size_t idx = (size_t)(row0 + wr + m * 16 + crow + r) * Nn + gc;
        if constexpr (sizeof(OutT) == 2) C[idx] = (OutT)f2bf(v);
        else                             C[idx] = v;
      }
}

// ------- paired-K GEMM2: 64x64 tile, NBUF=6, TWO K-tiles per barrier -------
// R13/R17 density knee: >=8 MFMAs/barrier amortizes the per-step fixed cost.
// 64x64/BK=32 has only 4; pairing gives 8 and halves barriers (32 -> 16).
// Ledger (L=2 loads/wave/stage): prologue stages tiles 0..3 (pairs 0,1).
// Iter p: vmcnt(4) => pair p landed (pair p+1's 2 stages stay in flight);
// barrier; stage pair p+2 into buffers (2p+4)%6,(2p+5)%6 (last read at
// iter p-1, behind the barrier); compute tiles 2p, 2p+1.
__global__ __launch_bounds__(256) void gemm2_paired(const unsigned short* __restrict__ A,
                                                    const unsigned short* __restrict__ W,
                                                    float* __restrict__ C,
                                                    int M, int Nn, int K) {
  constexpr int BM = 64, BN = 64, BK = 32, NBUF = 6;
  __shared__ unsigned short As[NBUF][BM * BK];
  __shared__ unsigned short Bs[NBUF][BN * BK];
  const int tid  = threadIdx.x;
  const int lane = tid & 63;
  const int wv   = tid >> 6;
  const int nwg  = gridDim.x * gridDim.y;
  int wgid = blockIdx.y * gridDim.x + blockIdx.x;
  wgid = (wgid & 7) * (nwg >> 3) + (wgid >> 3);
  const int row0 = (wgid / gridDim.x) * BM;
  const int col0 = (wgid % gridDim.x) * BN;
  const int ln15 = lane & 15;
  const int lhi  = lane >> 4;
  const int wr = (wv >> 1) * 32;
  const int wc = (wv & 1) * 32;

  f32x4 acc[2][2] = {};

  auto stage = [&](int buf, int t) {
    const int k0 = t * BK;
    const int lid = wv * 64 + lane;
    const int r  = lid >> 2;                // 0..63
    const int ke = (lid & 3) << 3;
    __builtin_amdgcn_global_load_lds(
        (const __attribute__((address_space(1))) void*)&A[(size_t)(row0 + r) * K + k0 + ke],
        (__attribute__((address_space(3))) void*)&As[buf][wv * 512], 16, 0, 0);
    __builtin_amdgcn_global_load_lds(
        (const __attribute__((address_space(1))) void*)&W[(size_t)(col0 + r) * K + k0 + ke],
        (__attribute__((address_space(3))) void*)&Bs[buf][wv * 512], 16, 0, 0);
  };

  const int nt = K / BK;                    // 32
  stage(0, 0); stage(1, 1); stage(2, 2); stage(3, 3);
  for (int p = 0; p < nt / 2; ++p) {        // 16 pairs
    if (p < nt / 2 - 1) asm volatile("s_waitcnt vmcnt(4)" ::: "memory");
    else                asm volatile("s_waitcnt vmcnt(0)" ::: "memory");
    __builtin_amdgcn_s_barrier();
    if (2 * p + 4 < nt) stage((2 * p + 4) % NBUF, 2 * p + 4);
    if (2 * p + 5 < nt) stage((2 * p + 5) % NBUF, 2 * p + 5);
#pragma unroll
    for (int half = 0; half < 2; ++half) {
      const int cur = (2 * p + half) % NBUF;
      bf16x8 a[2], b[2];
#pragma unroll
      for (int m = 0; m < 2; ++m)
        a[m] = *reinterpret_cast<const bf16x8*>(&As[cur][(wr + m * 16 + ln15) * BK + lhi * 8]);
#pragma unroll
      for (int n = 0; n < 2; ++n)
        b[n] = *reinterpret_cast<const bf16x8*>(&Bs[cur][(wc + n * 16 + ln15) * BK + lhi * 8]);
#pragma unroll
      for (int m = 0; m < 2; ++m)
#pragma unroll
        for (int n = 0; n < 2; ++n)
          acc[m][n] = __builtin_amdgcn_mfma_f32_16x16x32_bf16(a[m], b[n], acc[m][n], 0, 0, 0);
    }
  }

  const int crow = lhi * 4;           // m89-verified C/D layout
  const int ccol = ln15;
#pragma unroll
  for (int m = 0; m < 2; ++m)
#pragma unroll
    for (int n = 0; n < 2; ++n)
#pragma unroll
      for (int r = 0; r < 4; ++r) {
        const size_t idx = (size_t)(row0 + wr + m * 16 + crow + r) * Nn + col0 + wc + n * 16 + ccol;
        C[idx] = acc[m][n][r];
      }
}

// -------- MFMA per-(head,chunk) KV sums: ckv[h][c][d][e] = sum_r phik[r][d] v[r][e]
// (qkv K-columns already hold phi_k from GEMM1's fused epilogue)
__global__ __launch_bounds__(256) void ckv_mfma_kernel(const unsigned short* __restrict__ qkv,
                                                       float* __restrict__ ckv) {
  const int h = blockIdx.x / NCHUNK;
  const int c = blockIdx.x % NCHUNK;
  const int tid  = threadIdx.x;
  const int lane = tid & 63;
  const int w    = tid >> 6;        // wave = d-tile
  const int ln15 = lane & 15;
  const int lhi  = lane >> 4;

  __shared__ unsigned short kst[HD * CHUNK];   // phi_k^T [d][r] swizzled, 16 KB
  __shared__ unsigned short vt[HD * CHUNK];    // v^T     [e][r] swizzled, 16 KB

  for (int i = tid; i < CHUNK * HD / 4; i += 256) {   // 8 iters
    const int r = i >> 4;
    const int d4 = (i & 15) << 2;
    const size_t base = (size_t)(c * CHUNK + r) * QKV_COLS + h * HD + d4;
    ushort4 k4 = *reinterpret_cast<const ushort4*>(&qkv[base + DIM]);
    ushort4 v4 = *reinterpret_cast<const ushort4*>(&qkv[base + 2 * DIM]);
#pragma unroll
    for (int j = 0; j < 4; ++j) {
      const int d = d4 + j;
      *reinterpret_cast<unsigned short*>((char*)kst + swzb(d * 256 + r * 2, d)) = (&k4.x)[j];
      *reinterpret_cast<unsigned short*>((char*)vt + swzb(d * 256 + r * 2, d)) = (&v4.x)[j];
    }
  }
  __syncthreads();

  f32x4 acc[4] = {};
#pragma unroll
  for (int ks = 0; ks < 4; ++ks) {
    const int dr = w * 16 + ln15;
    bf16x8 a = *reinterpret_cast<const bf16x8*>((char*)kst + swzb(dr * 256 + (ks * 32 + lhi * 8) * 2, dr));
#pragma unroll
    for (int et = 0; et < 4; ++et) {
      const int er = et * 16 + ln15;
      bf16x8 b = *reinterpret_cast<const bf16x8*>((char*)vt + swzb(er * 256 + (ks * 32 + lhi * 8) * 2, er));
      acc[et] = __builtin_amdgcn_mfma_f32_16x16x32_bf16(a, b, acc[et], 0, 0, 0);
    }
  }
  const size_t base = (size_t)(h * NCHUNK + c) * (HD * HD);
#pragma unroll
  for (int et = 0; et < 4; ++et)
#pragma unroll
    for (int r = 0; r < 4; ++r)
      ckv[base + (size_t)(w * 16 + lhi * 4 + r) * HD + et * 16 + ln15] = acc[et][r];
}

// -------- MFMA attention (with inline exclusive prefix over ckv chunks) ----
// (qkv Q/K-columns already hold phi from GEMM1's fused epilogue)
__global__ __launch_bounds__(256) void attn_mfma_kernel(const unsigned short* __restrict__ qkv,
                                                        const float* __restrict__ ckv,
                                                        const float* __restrict__ alpha_log,
                                                        const float* __restrict__ beta_log,
                                                        unsigned short* __restrict__ attn_out) {
  const int h = blockIdx.x / NCHUNK;
  const int c = blockIdx.x % NCHUNK;
  const int tid  = threadIdx.x;
  const int lane = tid & 63;
  const int w    = tid >> 6;        // wave 0..3, owns rows w*32 .. w*32+31
  const int ln15 = lane & 15;
  const int lhi  = lane >> 4;       // 0..3

  __shared__ unsigned short ks[CHUNK * HD];      // phi_k [128][64] swizzled, 16 KB
  __shared__ unsigned short vst[HD * 256];       // [e][k]: 0..63 Sp_hi, 64..127 Sp_lo, 128..255 v^T; 32 KB
  __shared__ unsigned short ps[CHUNK * CHUNK];   // P [128][128] swizzled, 32 KB

  // ---- stage 1a: K/V into LDS + phi_q registers (issued FIRST so the
  //      global loads' latency hides under the prefix chain below) ----
  for (int i = tid; i < CHUNK * HD / 4; i += 256) {   // 8 iters
    const int r = i >> 4;
    const int d4 = (i & 15) << 2;
    const size_t base = (size_t)(c * CHUNK + r) * QKV_COLS + h * HD + d4;
    ushort4 k4 = *reinterpret_cast<const ushort4*>(&qkv[base + DIM]);
    ushort4 v4 = *reinterpret_cast<const ushort4*>(&qkv[base + 2 * DIM]);
    *reinterpret_cast<ushort4*>((char*)ks + swzb(r * 128 + d4 * 2, r)) = k4;
#pragma unroll
    for (int j = 0; j < 4; ++j) {
      const int e = d4 + j;
      *reinterpret_cast<unsigned short*>((char*)vst + swzb(e * 512 + (128 + r) * 2, e)) = (&v4.x)[j];
    }
  }
  bf16x8 qf[2][2];
#pragma unroll
  for (int m = 0; m < 2; ++m)
#pragma unroll
    for (int kk = 0; kk < 2; ++kk) {
      const size_t gq = (size_t)(c * CHUNK + w * 32 + m * 16 + ln15) * QKV_COLS
                        + h * HD + kk * 32 + lhi * 8;
      qf[m][kk] = *reinterpret_cast<const bf16x8*>(&qkv[gq]);
    }

  // ---- stage 1b: inline exclusive prefix: Sp = sum_{cc<c} ckv[h][cc] ----
  // 2-way unrolled: two independent chunk loads per iteration double the
  // ILP on the L2 load-latency chain (worst block c=15 halves its chain).
  {
    float sp[16];
#pragma unroll
    for (int p = 0; p < 16; ++p) sp[p] = 0.f;
    const float* cb = ckv + (size_t)h * NCHUNK * (HD * HD) + tid * 16;
    int cc = 0;
    for (; cc + 2 <= c; cc += 2) {
      const float4* pa = reinterpret_cast<const float4*>(cb + (size_t)cc * (HD * HD));
      const float4* pb = reinterpret_cast<const float4*>(cb + (size_t)(cc + 1) * (HD * HD));
#pragma unroll
      for (int q = 0; q < 4; ++q) {
        float4 t = pa[q];
        float4 u = pb[q];
        sp[q * 4 + 0] += t.x + u.x; sp[q * 4 + 1] += t.y + u.y;
        sp[q * 4 + 2] += t.z + u.z; sp[q * 4 + 3] += t.w + u.w;
      }
    }
    if (cc < c) {
      const float4* pa = reinterpret_cast<const float4*>(cb + (size_t)cc * (HD * HD));
#pragma unroll
      for (int q = 0; q < 4; ++q) {
        float4 t = pa[q];
        sp[q * 4 + 0] += t.x; sp[q * 4 + 1] += t.y;
        sp[q * 4 + 2] += t.z; sp[q * 4 + 3] += t.w;
      }
    }
    const int d = tid >> 2;
#pragma unroll
    for (int j = 0; j < 16; ++j) {
      const int e = (tid & 3) * 16 + j;
      const float sv = sp[j];
      const unsigned short hi = f2bf(sv);
      const unsigned short lo = f2bf(sv - bf2f(hi));
      *reinterpret_cast<unsigned short*>((char*)vst + swzb(e * 512 + d * 2, e)) = hi;
      *reinterpret_cast<unsigned short*>((char*)vst + swzb(e * 512 + (64 + d) * 2, e)) = lo;
    }
  }
  __syncthreads();

  // ---- stage 2: S = phi_q @ phi_k^T ----
  f32x4 accs[2][8] = {};
#pragma unroll
  for (int j = 0; j < 8; ++j) {
    const int col = j * 16 + ln15;
    bf16x8 b0 = *reinterpret_cast<const bf16x8*>((char*)ks + swzb(col * 128 + lhi * 16, col));
    bf16x8 b1 = *reinterpret_cast<const bf16x8*>((char*)ks + swzb(col * 128 + 64 + lhi * 16, col));
#pragma unroll
    for (int m = 0; m < 2; ++m) {
      accs[m][j] = __builtin_amdgcn_mfma_f32_16x16x32_bf16(qf[m][0], b0, accs[m][j], 0, 0, 0);
      accs[m][j] = __builtin_amdgcn_mfma_f32_16x16x32_bf16(qf[m][1], b1, accs[m][j], 0, 0, 0);
    }
  }
#pragma unroll
  for (int m = 0; m < 2; ++m)
#pragma unroll
    for (int j = 0; j < 8; ++j)
#pragma unroll
      for (int r = 0; r < 4; ++r) {
        const int qrow = w * 32 + m * 16 + lhi * 4 + r;
        const int kcol = j * 16 + ln15;
        const float val = (qrow >= kcol) ? accs[m][j][r] : 0.f;
        *reinterpret_cast<unsigned short*>((char*)ps + swzb(qrow * 256 + kcol * 2, qrow)) = f2bf(val);
      }
  __syncthreads();

  // ---- stage 3: out = [phi_q, phi_q, P] @ [Sp_hi; Sp_lo; v]  (K = 256) ----
  f32x4 acco[2][4] = {};
#pragma unroll
  for (int kk = 0; kk < 8; ++kk) {
    bf16x8 a[2];
    if (kk < 4) {
#pragma unroll
      for (int m = 0; m < 2; ++m) a[m] = qf[m][kk & 1];
    } else {
#pragma unroll
      for (int m = 0; m < 2; ++m) {
        const int row = w * 32 + m * 16 + ln15;
        a[m] = *reinterpret_cast<const bf16x8*>((char*)ps + swzb(row * 256 + (kk - 4) * 64 + lhi * 16, row));
      }
    }
#pragma unroll
    for (int ct = 0; ct < 4; ++ct) {
      const int e = ct * 16 + ln15;
      bf16x8 b = *reinterpret_cast<const bf16x8*>((char*)vst + swzb(e * 512 + kk * 64 + lhi * 16, e));
#pragma unroll
      for (int m = 0; m < 2; ++m)
        acco[m][ct] = __builtin_amdgcn_mfma_f32_16x16x32_bf16(a[m], b, acco[m][ct], 0, 0, 0);
    }
  }

  // ---- normalize + store ----
  const float ap = log1pf(expf(alpha_log[h])) + 1e-6f;
  const float bp = log1pf(expf(beta_log[h])) + 1e-6f;
  const float scale = ap * bp * 8.0f;     // sqrt(64)=8
#pragma unroll
  for (int m = 0; m < 2; ++m)
#pragma unroll
    for (int ct = 0; ct < 4; ++ct)
#pragma unroll
      for (int r = 0; r < 4; ++r) {
        const int n = c * CHUNK + w * 32 + m * 16 + lhi * 4 + r;
        const float inv = 1.0f / fmaxf(scale * (float)(n + 1), 1e-6f);
        attn_out[(size_t)n * DIM + h * HD + ct * 16 + ln15] = f2bf(acco[m][ct][r] * inv);
      }
}

extern "C" void kernel_launch(void* const* d_in, const int* in_sizes, int n_in,
                              void* d_out, int out_size, void* d_ws, size_t ws_size,
                              hipStream_t stream) {
  const float* x        = (const float*)d_in[0];
  const float* qkv_w    = (const float*)d_in[1];
  const float* proj_w   = (const float*)d_in[2];
  const float* alpha_lg = (const float*)d_in[3];
  const float* beta_lg  = (const float*)d_in[4];
  float* out = (float*)d_out;

  char* ws = (char*)d_ws;
  size_t off = 0;
  unsigned short* qkvb = (unsigned short*)(ws + off); off += (size_t)SEQ * QKV_COLS * 2;
  float*          ckv  = (float*)         (ws + off); off += (size_t)NH * NCHUNK * HD * HD * 4;
  unsigned short* attn = (unsigned short*)(ws + off); off += (size_t)SEQ * DIM * 2;
  unsigned short* xb   = (unsigned short*)(ws + off); off += (size_t)SEQ * DIM * 2;
  unsigned short* qwb  = (unsigned short*)(ws + off); off += (size_t)QKV_COLS * DIM * 2;
  unsigned short* pwb  = (unsigned short*)(ws + off); off += (size_t)DIM * DIM * 2;

  // 0) fused bf16 conversion (4 float4/thread)
  convert_all<<<1536, 256, 0, stream>>>(x, qkv_w, proj_w, xb, qwb, pwb);
  // 1) qkv = x @ qkv_w^T, phi fused (64x128 tile, NBUF=4, 768 blocks = 3/CU,
  //    unpaired: above density knee, TLP dominates -- R17/R18 verified)
  gemmN_bt<64, 128, 4, true, unsigned short><<<dim3(QKV_COLS / 128, SEQ / 64), 256, 0, stream>>>(
      xb, qwb, qkvb, SEQ, QKV_COLS, DIM);
  // 2) per-chunk KV sums via MFMA
  ckv_mfma_kernel<<<NH * NCHUNK, 256, 0, stream>>>(qkvb, ckv);
  // 3) attention (inline prefix, loads-first + 2-way unrolled prefix)
  attn_mfma_kernel<<<NH * NCHUNK, 256, 0, stream>>>(qkvb, ckv, alpha_lg, beta_lg, attn);
  // 4) out = attn @ proj_w^T (64x64 paired-K: 8 MFMAs/barrier, R17 proven)
  gemm2_paired<<<dim3(DIM / 64, SEQ / 64), 256, 0, stream>>>(
      attn, pwb, out, SEQ, DIM, DIM);
}